// Round 6
// baseline (338.928 us; speedup 1.0000x reference)
//
#include <hip/hip_runtime.h>
#include <math.h>

#define H 4096
#define H4 (H / 4)          // 1024 float4 per row
#define NCBLK (H / 16)      // 256 C-update blocks
#define NOBLK (H / 16)      // 256 Wo-gemv blocks
#define NBLK2 (NCBLK + NOBLK + 1)   // + 1 n-block

typedef float f4 __attribute__((ext_vector_type(4)));   // NT-builtin-compatible

__device__ __forceinline__ float wave_reduce_sum(float v) {
    #pragma unroll
    for (int off = 32; off > 0; off >>= 1)
        v += __shfl_down(v, off, 64);
    return v;
}

__device__ __forceinline__ float sigmoidf_(float x) {
    return 1.0f / (1.0f + __expf(-x));
}

__device__ __forceinline__ float dot4(f4 a, f4 b) {
    return a.x * b.x + a.y * b.y + a.z * b.z + a.w * b.w;
}

// Per-wave GEMV row: NT-load 16 KB row, dot against LDS-staged x.
__device__ __forceinline__ float gemv_row_nt(const f4* __restrict__ row4,
                                             const f4* __restrict__ xs,
                                             int lane) {
    float s = 0.0f;
    #pragma unroll
    for (int half = 0; half < 2; ++half) {
        const int base = half * 512;
        f4 a0 = __builtin_nontemporal_load(&row4[lane + base +   0]);
        f4 a1 = __builtin_nontemporal_load(&row4[lane + base +  64]);
        f4 a2 = __builtin_nontemporal_load(&row4[lane + base + 128]);
        f4 a3 = __builtin_nontemporal_load(&row4[lane + base + 192]);
        f4 a4_ = __builtin_nontemporal_load(&row4[lane + base + 256]);
        f4 a5 = __builtin_nontemporal_load(&row4[lane + base + 320]);
        f4 a6 = __builtin_nontemporal_load(&row4[lane + base + 384]);
        f4 a7 = __builtin_nontemporal_load(&row4[lane + base + 448]);
        s += dot4(a0,  xs[lane + base +   0]);
        s += dot4(a1,  xs[lane + base +  64]);
        s += dot4(a2,  xs[lane + base + 128]);
        s += dot4(a3,  xs[lane + base + 192]);
        s += dot4(a4_, xs[lane + base + 256]);
        s += dot4(a5,  xs[lane + base + 320]);
        s += dot4(a6,  xs[lane + base + 384]);
        s += dot4(a7,  xs[lane + base + 448]);
    }
    return s;
}

// Kernel 1: q/k/v GEMVs + wi/wf dots. One wave per row, 16 waves/block,
// NT loads on W (single-pass; bypassing L3 allocation broke the 2.8 TB/s
// L3-lookup cap in round 4).
__global__ __launch_bounds__(1024) void gemv_qkv(
    const float* __restrict__ x,
    const float* __restrict__ Wq, const float* __restrict__ Wk,
    const float* __restrict__ Wv,
    const float* __restrict__ bq, const float* __restrict__ bk,
    const float* __restrict__ bv,
    const float* __restrict__ wi, const float* __restrict__ wf,
    float* __restrict__ q, float* __restrict__ k,
    float* __restrict__ v, float* __restrict__ s2)
{
    const int tid  = threadIdx.x;
    const int wave = tid >> 6;
    const int lane = tid & 63;

    __shared__ f4 xs[H4];                 // 16 KB, one stage for 16 rows
    const f4* x4 = (const f4*)x;
    xs[tid] = x4[tid];
    __syncthreads();

    const int rowId = blockIdx.x * 16 + wave;
    if (rowId >= 3 * H + 2) return;

    const int m = rowId >> 12;            // 0=q 1=k 2=v when < 12288
    const int r = rowId & (H - 1);

    const float* row;
    if (rowId < 3 * H) {
        const float* W = (m == 0) ? Wq : (m == 1) ? Wk : Wv;
        row = W + (size_t)r * H;
    } else {
        row = (rowId == 3 * H) ? wi : wf;
    }

    float s = gemv_row_nt((const f4*)row, xs, lane);
    s = wave_reduce_sum(s);

    if (lane == 0) {
        if (rowId < 3 * H) {
            if (m == 0)      q[r] = s + bq[r];
            else if (m == 1) k[r] = (s + bk[r]) * 0.015625f;  // 1/sqrt(4096)
            else             v[r] = s + bv[r];
        } else {
            s2[rowId - 3 * H] = s;   // s2[0] = wi.x, s2[1] = wf.x (raw dots)
        }
    }
}

// Kernel 2: everything else, three block families + last-block epilogue.
//  [0, NCBLK):            C = f*C_prev + (i*v[r])*k (NT in/out), and
//                         u[r] = C_prev[r,:].q from the same loads.
//  [NCBLK, NCBLK+NOBLK):  Wo GEMV + output gate (needs only x).
//  NCBLK+NOBLK:           n_out = f*n_prev + i*k; nq = n.q; kq = k.q.
//  LAST FINISHER (atomic ticket, any family): h = og*(f*u+i*v*kq)/denom.
//  cnt must be zeroed before launch (hipMemsetAsync in kernel_launch).
__global__ __launch_bounds__(1024) void c_update_o(
    const float* __restrict__ C_prev,
    const float* __restrict__ x,
    const float* __restrict__ Wo, const float* __restrict__ bo,
    const float* __restrict__ n_prev,
    const float* __restrict__ q, const float* __restrict__ k,
    const float* __restrict__ v, const float* __restrict__ s2,
    const float* __restrict__ bi, const float* __restrict__ bf,
    float* __restrict__ C_out, float* __restrict__ u,
    float* __restrict__ og, float* __restrict__ n_out,
    float* __restrict__ nqkq, int* __restrict__ cnt,
    float* __restrict__ h)
{
    const int tid  = threadIdx.x;
    const int wave = tid >> 6;
    const int lane = tid & 63;

    __shared__ f4 lds[2 * H4];            // 32 KB (qs+ks, or xs in og blocks)

    const float ig = __expf(s2[0] + bi[0]);
    const float fg = sigmoidf_(s2[1] + bf[0]);

    if (blockIdx.x < NCBLK) {
        // ---- C-update family ----
        f4* qs = lds;
        f4* ks = lds + H4;
        const f4* q4 = (const f4*)q;
        const f4* k4 = (const f4*)k;
        qs[tid] = q4[tid];
        ks[tid] = k4[tid];
        __syncthreads();

        const int r = blockIdx.x * 16 + wave;
        const float ivr = ig * v[r];

        const f4* c4 = (const f4*)(C_prev + (size_t)r * H);
        f4*       o4 = (f4*)(C_out + (size_t)r * H);

        float acc = 0.0f;
        #pragma unroll
        for (int half = 0; half < 2; ++half) {
            const int base = half * 512;
            f4 a0 = __builtin_nontemporal_load(&c4[lane + base +   0]);
            f4 a1 = __builtin_nontemporal_load(&c4[lane + base +  64]);
            f4 a2 = __builtin_nontemporal_load(&c4[lane + base + 128]);
            f4 a3 = __builtin_nontemporal_load(&c4[lane + base + 192]);
            f4 a4_ = __builtin_nontemporal_load(&c4[lane + base + 256]);
            f4 a5 = __builtin_nontemporal_load(&c4[lane + base + 320]);
            f4 a6 = __builtin_nontemporal_load(&c4[lane + base + 384]);
            f4 a7 = __builtin_nontemporal_load(&c4[lane + base + 448]);

            f4 o;
            #define CONSUME(reg, off)                                    \
                {                                                        \
                    f4 kk = ks[lane + (off)];                            \
                    o.x = fg * reg.x + ivr * kk.x;                       \
                    o.y = fg * reg.y + ivr * kk.y;                       \
                    o.z = fg * reg.z + ivr * kk.z;                       \
                    o.w = fg * reg.w + ivr * kk.w;                       \
                    __builtin_nontemporal_store(o, &o4[lane + (off)]);   \
                    acc += dot4(reg, qs[lane + (off)]);                  \
                }
            CONSUME(a0, base +   0) CONSUME(a1, base +  64)
            CONSUME(a2, base + 128) CONSUME(a3, base + 192)
            CONSUME(a4_, base + 256) CONSUME(a5, base + 320)
            CONSUME(a6, base + 384) CONSUME(a7, base + 448)
            #undef CONSUME
        }

        acc = wave_reduce_sum(acc);
        if (lane == 0) u[r] = acc;
    } else if (blockIdx.x < NCBLK + NOBLK) {
        // ---- Wo GEMV + sigmoid family (depends only on x) ----
        f4* xs = lds;
        const f4* x4 = (const f4*)x;
        xs[tid] = x4[tid];
        __syncthreads();

        const int r = (blockIdx.x - NCBLK) * 16 + wave;
        const f4* row4 = (const f4*)(Wo + (size_t)r * H);

        float s = gemv_row_nt(row4, xs, lane);
        s = wave_reduce_sum(s);
        if (lane == 0) og[r] = sigmoidf_(s + bo[r]);
    } else {
        // ---- n-block: n_out, nq, kq (1024 threads, one f4 each) ----
        const f4* np4 = (const f4*)n_prev;
        const f4* q4  = (const f4*)q;
        const f4* k4  = (const f4*)k;
        f4* no4 = (f4*)n_out;

        f4 kk = k4[tid];
        f4 qq = q4[tid];
        f4 nn = np4[tid];
        f4 no;
        no.x = fg * nn.x + ig * kk.x;
        no.y = fg * nn.y + ig * kk.y;
        no.z = fg * nn.z + ig * kk.z;
        no.w = fg * nn.w + ig * kk.w;
        no4[tid] = no;
        float nq = dot4(no, qq);
        float kq = dot4(kk, qq);
        nq = wave_reduce_sum(nq);
        kq = wave_reduce_sum(kq);

        __shared__ float snq[16], skq[16];
        if (lane == 0) { snq[wave] = nq; skq[wave] = kq; }
        __syncthreads();
        if (tid == 0) {
            float a = 0.0f, b = 0.0f;
            #pragma unroll
            for (int w = 0; w < 16; ++w) { a += snq[w]; b += skq[w]; }
            nqkq[0] = a;
            nqkq[1] = b;
        }
    }

    // ---- last-finisher epilogue: h = og * (f*u + i*v*kq) / denom ----
    __shared__ int is_last;
    __syncthreads();                       // all this block's work issued
    if (tid == 0) {
        __threadfence();                   // publish this block's writes
        int old = atomicAdd(cnt, 1);
        is_last = (old == NBLK2 - 1);
    }
    __syncthreads();
    if (is_last) {
        __threadfence();                   // acquire other blocks' writes
        const float nqv = nqkq[0];
        const float kqv = nqkq[1];
        const float inv_denom = 1.0f / fmaxf(fabsf(nqv), 1.0f);
        const f4* u4  = (const f4*)u;
        const f4* v4  = (const f4*)v;
        const f4* og4 = (const f4*)og;
        f4* h4 = (f4*)h;
        f4 uu = u4[tid];
        f4 vv = v4[tid];
        f4 oo = og4[tid];
        f4 hh;
        hh.x = oo.x * (fg * uu.x + ig * vv.x * kqv) * inv_denom;
        hh.y = oo.y * (fg * uu.y + ig * vv.y * kqv) * inv_denom;
        hh.z = oo.z * (fg * uu.z + ig * vv.z * kqv) * inv_denom;
        hh.w = oo.w * (fg * uu.w + ig * vv.w * kqv) * inv_denom;
        h4[tid] = hh;
    }
}

extern "C" void kernel_launch(void* const* d_in, const int* in_sizes, int n_in,
                              void* d_out, int out_size, void* d_ws, size_t ws_size,
                              hipStream_t stream) {
    const float* x      = (const float*)d_in[0];
    // d_in[1] = h_prev (unused by mLSTM math)
    const float* C_prev = (const float*)d_in[2];
    const float* n_prev = (const float*)d_in[3];
    const float* Wq     = (const float*)d_in[4];
    const float* Wk     = (const float*)d_in[5];
    const float* Wv     = (const float*)d_in[6];
    const float* Wo     = (const float*)d_in[7];
    const float* bq     = (const float*)d_in[8];
    const float* bk     = (const float*)d_in[9];
    const float* bv     = (const float*)d_in[10];
    const float* bo     = (const float*)d_in[11];
    const float* wi     = (const float*)d_in[12];
    const float* bi     = (const float*)d_in[13];
    const float* wf     = (const float*)d_in[14];
    const float* bf     = (const float*)d_in[15];

    float* out   = (float*)d_out;
    float* h_out = out;                       // [H]
    float* C_out = out + H;                   // [H*H]
    float* n_out = out + H + (size_t)H * H;   // [H]

    float* ws   = (float*)d_ws;
    float* q    = ws;
    float* k    = ws + H;
    float* v    = ws + 2 * H;
    float* og   = ws + 3 * H;
    float* u    = ws + 4 * H;
    float* s2   = ws + 5 * H;                 // 2 floats
    float* nqkq = ws + 5 * H + 2;             // 2 floats
    int*   cnt  = (int*)(ws + 5 * H + 4);     // 1 int ticket counter

    // Zero the ticket counter (graph-capture-safe async memset).
    hipMemsetAsync(cnt, 0, sizeof(int), stream);

    // Kernel 1: q/k/v (3*H rows) + wi/wf dots, one wave per row.
    const int nrows1 = 3 * H + 2;
    const int blocks1 = (nrows1 + 15) / 16;
    gemv_qkv<<<blocks1, 1024, 0, stream>>>(x, Wq, Wk, Wv, bq, bk, bv,
                                           wi, wf, q, k, v, s2);

    // Kernel 2: C-update + Wo GEMV + n-block + last-finisher epilogue.
    c_update_o<<<NBLK2, 1024, 0, stream>>>(C_prev, x, Wo, bo, n_prev,
                                           q, k, v, s2, bi, bf,
                                           C_out, u, og, n_out,
                                           nqkq, cnt, h_out);
}

// Round 8
// 313.904 us; speedup vs baseline: 1.0797x; 1.0797x over previous
//
#include <hip/hip_runtime.h>
#include <math.h>

#define H 4096
#define H4 (H / 4)          // 1024 float4 per row
#define NCBLK (H / 16)      // 256 C-update blocks
#define NOBLK (H / 16)      // 256 Wo-gemv blocks
#define NBLK2 (NCBLK + NOBLK + 1)   // + 1 n-block (independent, fence-free)

typedef float f4 __attribute__((ext_vector_type(4)));   // NT-builtin-compatible

__device__ __forceinline__ float wave_reduce_sum(float v) {
    #pragma unroll
    for (int off = 32; off > 0; off >>= 1)
        v += __shfl_down(v, off, 64);
    return v;
}

__device__ __forceinline__ float sigmoidf_(float x) {
    return 1.0f / (1.0f + __expf(-x));
}

__device__ __forceinline__ float dot4(f4 a, f4 b) {
    return a.x * b.x + a.y * b.y + a.z * b.z + a.w * b.w;
}

// Per-wave GEMV row: NT-load 16 KB row, dot against LDS-staged x.
__device__ __forceinline__ float gemv_row_nt(const f4* __restrict__ row4,
                                             const f4* __restrict__ xs,
                                             int lane) {
    float s = 0.0f;
    #pragma unroll
    for (int half = 0; half < 2; ++half) {
        const int base = half * 512;
        f4 a0 = __builtin_nontemporal_load(&row4[lane + base +   0]);
        f4 a1 = __builtin_nontemporal_load(&row4[lane + base +  64]);
        f4 a2 = __builtin_nontemporal_load(&row4[lane + base + 128]);
        f4 a3 = __builtin_nontemporal_load(&row4[lane + base + 192]);
        f4 a4_ = __builtin_nontemporal_load(&row4[lane + base + 256]);
        f4 a5 = __builtin_nontemporal_load(&row4[lane + base + 320]);
        f4 a6 = __builtin_nontemporal_load(&row4[lane + base + 384]);
        f4 a7 = __builtin_nontemporal_load(&row4[lane + base + 448]);
        s += dot4(a0,  xs[lane + base +   0]);
        s += dot4(a1,  xs[lane + base +  64]);
        s += dot4(a2,  xs[lane + base + 128]);
        s += dot4(a3,  xs[lane + base + 192]);
        s += dot4(a4_, xs[lane + base + 256]);
        s += dot4(a5,  xs[lane + base + 320]);
        s += dot4(a6,  xs[lane + base + 384]);
        s += dot4(a7,  xs[lane + base + 448]);
    }
    return s;
}

// Kernel 1: q/k/v GEMVs + wi/wf dots. One wave per row, 16 waves/block,
// NT loads on W (single-pass; bypassing L3 allocation broke the 2.8 TB/s
// L3-lookup cap in round 4).
__global__ __launch_bounds__(1024) void gemv_qkv(
    const float* __restrict__ x,
    const float* __restrict__ Wq, const float* __restrict__ Wk,
    const float* __restrict__ Wv,
    const float* __restrict__ bq, const float* __restrict__ bk,
    const float* __restrict__ bv,
    const float* __restrict__ wi, const float* __restrict__ wf,
    float* __restrict__ q, float* __restrict__ k,
    float* __restrict__ v, float* __restrict__ s2)
{
    const int tid  = threadIdx.x;
    const int wave = tid >> 6;
    const int lane = tid & 63;

    __shared__ f4 xs[H4];                 // 16 KB, one stage for 16 rows
    const f4* x4 = (const f4*)x;
    xs[tid] = x4[tid];
    __syncthreads();

    const int rowId = blockIdx.x * 16 + wave;
    if (rowId >= 3 * H + 2) return;

    const int m = rowId >> 12;            // 0=q 1=k 2=v when < 12288
    const int r = rowId & (H - 1);

    const float* row;
    if (rowId < 3 * H) {
        const float* W = (m == 0) ? Wq : (m == 1) ? Wk : Wv;
        row = W + (size_t)r * H;
    } else {
        row = (rowId == 3 * H) ? wi : wf;
    }

    float s = gemv_row_nt((const f4*)row, xs, lane);
    s = wave_reduce_sum(s);

    if (lane == 0) {
        if (rowId < 3 * H) {
            if (m == 0)      q[r] = s + bq[r];
            else if (m == 1) k[r] = (s + bk[r]) * 0.015625f;  // 1/sqrt(4096)
            else             v[r] = s + bv[r];
        } else {
            s2[rowId - 3 * H] = s;   // s2[0] = wi.x, s2[1] = wf.x (raw dots)
        }
    }
}

// Kernel 2: three INDEPENDENT block families, no cross-block sync.
//  [0, NCBLK):            C = f*C_prev + (i*v[r])*k (NT in/out), and
//                         u[r] = C_prev[r,:].q from the same loads.
//  [NCBLK, NCBLK+NOBLK):  Wo GEMV + output gate (needs only x).
//  NCBLK+NOBLK:           n_out = f*n_prev + i*k; nqkq = {n.q, k.q}.
__global__ __launch_bounds__(1024) void c_update_o(
    const float* __restrict__ C_prev,
    const float* __restrict__ x,
    const float* __restrict__ Wo, const float* __restrict__ bo,
    const float* __restrict__ n_prev,
    const float* __restrict__ q, const float* __restrict__ k,
    const float* __restrict__ v, const float* __restrict__ s2,
    const float* __restrict__ bi, const float* __restrict__ bf,
    float* __restrict__ C_out, float* __restrict__ u,
    float* __restrict__ og, float* __restrict__ n_out,
    float* __restrict__ nqkq)
{
    const int tid  = threadIdx.x;
    const int wave = tid >> 6;
    const int lane = tid & 63;

    __shared__ f4 lds[2 * H4];            // 32 KB (qs+ks, or xs in og blocks)

    const float ig = __expf(s2[0] + bi[0]);
    const float fg = sigmoidf_(s2[1] + bf[0]);

    if (blockIdx.x < NCBLK) {
        // ---- C-update family ----
        f4* qs = lds;
        f4* ks = lds + H4;
        const f4* q4 = (const f4*)q;
        const f4* k4 = (const f4*)k;
        qs[tid] = q4[tid];
        ks[tid] = k4[tid];
        __syncthreads();

        const int r = blockIdx.x * 16 + wave;
        const float ivr = ig * v[r];

        const f4* c4 = (const f4*)(C_prev + (size_t)r * H);
        f4*       o4 = (f4*)(C_out + (size_t)r * H);

        float acc = 0.0f;
        #pragma unroll
        for (int half = 0; half < 2; ++half) {
            const int base = half * 512;
            f4 a0 = __builtin_nontemporal_load(&c4[lane + base +   0]);
            f4 a1 = __builtin_nontemporal_load(&c4[lane + base +  64]);
            f4 a2 = __builtin_nontemporal_load(&c4[lane + base + 128]);
            f4 a3 = __builtin_nontemporal_load(&c4[lane + base + 192]);
            f4 a4_ = __builtin_nontemporal_load(&c4[lane + base + 256]);
            f4 a5 = __builtin_nontemporal_load(&c4[lane + base + 320]);
            f4 a6 = __builtin_nontemporal_load(&c4[lane + base + 384]);
            f4 a7 = __builtin_nontemporal_load(&c4[lane + base + 448]);

            f4 o;
            #define CONSUME(reg, off)                                    \
                {                                                        \
                    f4 kk = ks[lane + (off)];                            \
                    o.x = fg * reg.x + ivr * kk.x;                       \
                    o.y = fg * reg.y + ivr * kk.y;                       \
                    o.z = fg * reg.z + ivr * kk.z;                       \
                    o.w = fg * reg.w + ivr * kk.w;                       \
                    __builtin_nontemporal_store(o, &o4[lane + (off)]);   \
                    acc += dot4(reg, qs[lane + (off)]);                  \
                }
            CONSUME(a0, base +   0) CONSUME(a1, base +  64)
            CONSUME(a2, base + 128) CONSUME(a3, base + 192)
            CONSUME(a4_, base + 256) CONSUME(a5, base + 320)
            CONSUME(a6, base + 384) CONSUME(a7, base + 448)
            #undef CONSUME
        }

        acc = wave_reduce_sum(acc);
        if (lane == 0) u[r] = acc;
    } else if (blockIdx.x < NCBLK + NOBLK) {
        // ---- Wo GEMV + sigmoid family (depends only on x) ----
        f4* xs = lds;
        const f4* x4 = (const f4*)x;
        xs[tid] = x4[tid];
        __syncthreads();

        const int r = (blockIdx.x - NCBLK) * 16 + wave;
        const f4* row4 = (const f4*)(Wo + (size_t)r * H);

        float s = gemv_row_nt(row4, xs, lane);
        s = wave_reduce_sum(s);
        if (lane == 0) og[r] = sigmoidf_(s + bo[r]);
    } else {
        // ---- n-block: n_out, nq, kq (1024 threads, one f4 each) ----
        const f4* np4 = (const f4*)n_prev;
        const f4* q4  = (const f4*)q;
        const f4* k4  = (const f4*)k;
        f4* no4 = (f4*)n_out;

        f4 kk = k4[tid];
        f4 qq = q4[tid];
        f4 nn = np4[tid];
        f4 no;
        no.x = fg * nn.x + ig * kk.x;
        no.y = fg * nn.y + ig * kk.y;
        no.z = fg * nn.z + ig * kk.z;
        no.w = fg * nn.w + ig * kk.w;
        no4[tid] = no;
        float nq = dot4(no, qq);
        float kq = dot4(kk, qq);
        nq = wave_reduce_sum(nq);
        kq = wave_reduce_sum(kq);

        __shared__ float snq[16], skq[16];
        if (lane == 0) { snq[wave] = nq; skq[wave] = kq; }
        __syncthreads();
        if (tid == 0) {
            float a = 0.0f, b = 0.0f;
            #pragma unroll
            for (int w = 0; w < 16; ++w) { a += snq[w]; b += skq[w]; }
            nqkq[0] = a;
            nqkq[1] = b;
        }
    }
}

// Kernel 3: tiny elementwise epilogue — h = og*(f*u + i*v*kq)/denom.
// Single block, one f4 per thread. Ordering vs K2 via stream.
__global__ __launch_bounds__(1024) void finalize_h(
    const float* __restrict__ v, const float* __restrict__ og,
    const float* __restrict__ u, const float* __restrict__ s2,
    const float* __restrict__ nqkq,
    const float* __restrict__ bi, const float* __restrict__ bf,
    float* __restrict__ h)
{
    const int tid = threadIdx.x;

    const float ig = __expf(s2[0] + bi[0]);
    const float fg = sigmoidf_(s2[1] + bf[0]);
    const float kqv = nqkq[1];
    const float inv_denom = 1.0f / fmaxf(fabsf(nqkq[0]), 1.0f);

    const f4* u4  = (const f4*)u;
    const f4* v4  = (const f4*)v;
    const f4* og4 = (const f4*)og;
    f4* h4 = (f4*)h;

    f4 uu = u4[tid];
    f4 vv = v4[tid];
    f4 oo = og4[tid];
    f4 hh;
    hh.x = oo.x * (fg * uu.x + ig * vv.x * kqv) * inv_denom;
    hh.y = oo.y * (fg * uu.y + ig * vv.y * kqv) * inv_denom;
    hh.z = oo.z * (fg * uu.z + ig * vv.z * kqv) * inv_denom;
    hh.w = oo.w * (fg * uu.w + ig * vv.w * kqv) * inv_denom;
    h4[tid] = hh;
}

extern "C" void kernel_launch(void* const* d_in, const int* in_sizes, int n_in,
                              void* d_out, int out_size, void* d_ws, size_t ws_size,
                              hipStream_t stream) {
    const float* x      = (const float*)d_in[0];
    // d_in[1] = h_prev (unused by mLSTM math)
    const float* C_prev = (const float*)d_in[2];
    const float* n_prev = (const float*)d_in[3];
    const float* Wq     = (const float*)d_in[4];
    const float* Wk     = (const float*)d_in[5];
    const float* Wv     = (const float*)d_in[6];
    const float* Wo     = (const float*)d_in[7];
    const float* bq     = (const float*)d_in[8];
    const float* bk     = (const float*)d_in[9];
    const float* bv     = (const float*)d_in[10];
    const float* bo     = (const float*)d_in[11];
    const float* wi     = (const float*)d_in[12];
    const float* bi     = (const float*)d_in[13];
    const float* wf     = (const float*)d_in[14];
    const float* bf     = (const float*)d_in[15];

    float* out   = (float*)d_out;
    float* h_out = out;                       // [H]
    float* C_out = out + H;                   // [H*H]
    float* n_out = out + H + (size_t)H * H;   // [H]

    float* ws   = (float*)d_ws;
    float* q    = ws;
    float* k    = ws + H;
    float* v    = ws + 2 * H;
    float* og   = ws + 3 * H;
    float* u    = ws + 4 * H;
    float* s2   = ws + 5 * H;                 // 2 floats
    float* nqkq = ws + 5 * H + 2;             // 2 floats

    // Kernel 1: q/k/v (3*H rows) + wi/wf dots, one wave per row.
    const int nrows1 = 3 * H + 2;
    const int blocks1 = (nrows1 + 15) / 16;
    gemv_qkv<<<blocks1, 1024, 0, stream>>>(x, Wq, Wk, Wv, bq, bk, bv,
                                           wi, wf, q, k, v, s2);

    // Kernel 2: C-update + Wo GEMV + n-block (independent families).
    c_update_o<<<NBLK2, 1024, 0, stream>>>(C_prev, x, Wo, bo, n_prev,
                                           q, k, v, s2, bi, bf,
                                           C_out, u, og, n_out, nqkq);

    // Kernel 3: single-block elementwise h epilogue.
    finalize_h<<<1, 1024, 0, stream>>>(v, og, u, s2, nqkq, bi, bf, h_out);
}